// Round 3
// baseline (12.550 us; speedup 1.0000x reference)
//
#include <hip/hip_runtime.h>

// Analytic reduction of the 3-qubit circuit:
//   CNOT(0,1) and CNOT(1,2) preserve the b0 index -> commute with Z_0.
//   Qubit 0 state = RY(theta0)*RY(p0)|0> = [cos((p0+t0)/2), sin((p0+t0)/2)]
//   <Z_0> = cos^2 - sin^2 = cos(p0 + theta0).
// So out[i] = cos(patches[3*i] + theta[0]). Pure memory-bound streaming.
// __cosf -> hardware v_cos_f32 (err ~1e-5, threshold 2e-2).

typedef float f32x4 __attribute__((ext_vector_type(4)));  // clang vector: OK for nontemporal builtins

__global__ __launch_bounds__(256) void qconv3_vec8_kernel(
    const float* __restrict__ patches,   // [B,3] flat
    const float* __restrict__ theta,     // [3]
    float* __restrict__ out,             // [B]
    int n8)                              // B/8
{
    int t = blockIdx.x * blockDim.x + threadIdx.x;
    if (t >= n8) return;
    float t0 = theta[0];
    const f32x4* p = reinterpret_cast<const f32x4*>(patches) + 6 * (size_t)t;
    // 8 patches = 24 floats = 6 float4s; column-0 at flat 0,3,6,9,12,15,18,21
    f32x4 v0 = __builtin_nontemporal_load(p + 0);
    f32x4 v1 = __builtin_nontemporal_load(p + 1);
    f32x4 v2 = __builtin_nontemporal_load(p + 2);
    f32x4 v3 = __builtin_nontemporal_load(p + 3);
    f32x4 v4 = __builtin_nontemporal_load(p + 4);
    f32x4 v5 = __builtin_nontemporal_load(p + 5);
    f32x4 oa, ob;
    oa.x = __cosf(v0.x + t0);   // flat 24t+0
    oa.y = __cosf(v0.w + t0);   // flat 24t+3
    oa.z = __cosf(v1.z + t0);   // flat 24t+6
    oa.w = __cosf(v2.y + t0);   // flat 24t+9
    ob.x = __cosf(v3.x + t0);   // flat 24t+12
    ob.y = __cosf(v3.w + t0);   // flat 24t+15
    ob.z = __cosf(v4.z + t0);   // flat 24t+18
    ob.w = __cosf(v5.y + t0);   // flat 24t+21
    f32x4* o = reinterpret_cast<f32x4*>(out) + 2 * (size_t)t;
    __builtin_nontemporal_store(oa, o + 0);
    __builtin_nontemporal_store(ob, o + 1);
}

// Scalar fallback for any tail (B=2097152 is divisible by 8, so unused here).
__global__ __launch_bounds__(256) void qconv3_scalar_kernel(
    const float* __restrict__ patches,
    const float* __restrict__ theta,
    float* __restrict__ out,
    int n, int start)
{
    int i = start + blockIdx.x * blockDim.x + threadIdx.x;
    if (i >= n) return;
    out[i] = __cosf(patches[3 * (size_t)i] + theta[0]);
}

extern "C" void kernel_launch(void* const* d_in, const int* in_sizes, int n_in,
                              void* d_out, int out_size, void* d_ws, size_t ws_size,
                              hipStream_t stream) {
    const float* patches = (const float*)d_in[0];
    const float* theta   = (const float*)d_in[1];
    float* out = (float*)d_out;

    int n  = out_size;          // B
    int n8 = n / 8;
    if (n8 > 0) {
        int blocks = (n8 + 255) / 256;
        qconv3_vec8_kernel<<<blocks, 256, 0, stream>>>(patches, theta, out, n8);
    }
    int tail = n - n8 * 8;
    if (tail > 0) {
        qconv3_scalar_kernel<<<1, 256, 0, stream>>>(patches, theta, out, n, n8 * 8);
    }
}

// Round 4
// 10.368 us; speedup vs baseline: 1.2104x; 1.2104x over previous
//
#include <hip/hip_runtime.h>

// Analytic reduction of the 3-qubit circuit:
//   CNOT(0,1) and CNOT(1,2) preserve the b0 index -> commute with Z_0.
//   Qubit 0 state = RY(theta0)*RY(p0)|0> = [cos((p0+t0)/2), sin((p0+t0)/2)]
//   <Z_0> = cos^2 - sin^2 = cos(p0 + theta0).
// So out[i] = cos(patches[3*i] + theta[0]). Pure memory-bound streaming.
// Round-1 structure (4 patches/thread, 2048 blocks, plain loads) + __cosf.
// Nontemporal hints and 8/thread (round 3) regressed: 10.45 -> 12.55 us.

__global__ __launch_bounds__(256) void qconv3_vec4_kernel(
    const float* __restrict__ patches,   // [B,3] flat
    const float* __restrict__ theta,     // [3]
    float* __restrict__ out,             // [B]
    int n4)                              // B/4
{
    int t = blockIdx.x * blockDim.x + threadIdx.x;
    if (t >= n4) return;
    float t0 = theta[0];
    const float4* p = reinterpret_cast<const float4*>(patches) + 3 * (size_t)t;
    float4 v0 = p[0];   // patches[12t+0 .. 12t+3]
    float4 v1 = p[1];   // patches[12t+4 .. 12t+7]
    float4 v2 = p[2];   // patches[12t+8 .. 12t+11]
    float4 o;
    o.x = __cosf(v0.x + t0);   // patch 4t+0, elem 0 -> flat 12t+0
    o.y = __cosf(v0.w + t0);   // patch 4t+1, elem 0 -> flat 12t+3
    o.z = __cosf(v1.z + t0);   // patch 4t+2, elem 0 -> flat 12t+6
    o.w = __cosf(v2.y + t0);   // patch 4t+3, elem 0 -> flat 12t+9
    reinterpret_cast<float4*>(out)[t] = o;
}

// Scalar fallback for any tail (B=2097152 divisible by 4, so unused here).
__global__ __launch_bounds__(256) void qconv3_scalar_kernel(
    const float* __restrict__ patches,
    const float* __restrict__ theta,
    float* __restrict__ out,
    int n, int start)
{
    int i = start + blockIdx.x * blockDim.x + threadIdx.x;
    if (i >= n) return;
    out[i] = __cosf(patches[3 * (size_t)i] + theta[0]);
}

extern "C" void kernel_launch(void* const* d_in, const int* in_sizes, int n_in,
                              void* d_out, int out_size, void* d_ws, size_t ws_size,
                              hipStream_t stream) {
    const float* patches = (const float*)d_in[0];
    const float* theta   = (const float*)d_in[1];
    float* out = (float*)d_out;

    int n  = out_size;          // B
    int n4 = n / 4;
    if (n4 > 0) {
        int blocks = (n4 + 255) / 256;
        qconv3_vec4_kernel<<<blocks, 256, 0, stream>>>(patches, theta, out, n4);
    }
    int tail = n - n4 * 4;
    if (tail > 0) {
        qconv3_scalar_kernel<<<1, 256, 0, stream>>>(patches, theta, out, n, n4 * 4);
    }
}